// Round 8
// baseline (202.631 us; speedup 1.0000x reference)
//
#include <hip/hip_runtime.h>
#include <stdint.h>

#define NN3 262144
#define NN2 65536
#define NN1 16384

typedef __attribute__((ext_vector_type(8))) __bf16 bf16x8;
typedef __attribute__((ext_vector_type(4))) float floatx4;
typedef __attribute__((ext_vector_type(4))) unsigned int uint4v;

static __device__ __forceinline__ float bf2f(unsigned short u) {
    union { unsigned int i; float f; } v; v.i = ((unsigned int)u) << 16; return v.f;
}
static __device__ __forceinline__ unsigned short f2bf(float f) {
    union { float f; unsigned int i; } v; v.f = f;
    unsigned int x = v.i;
    return (unsigned short)((x + 0x7fffu + ((x >> 16) & 1u)) >> 16);
}
static __device__ __forceinline__ bf16x8 zero_bf16x8() {
    bf16x8 z;
#pragma unroll
    for (int i = 0; i < 8; ++i) z[i] = (__bf16)0.0f;
    return z;
}

// ---------------- enc1 + pool1 fused, weight prep folded in; wave-private staging ----------------
__global__ __launch_bounds__(256) void enc1pool_kernel(
    const float* __restrict__ feat, const int* __restrict__ neigh,
    const float* __restrict__ w, const float* __restrict__ b,
    unsigned short* __restrict__ x7p,
    const float* __restrict__ w_enc2, const float* __restrict__ w_enc3,
    const float* __restrict__ w_dec1, const float* __restrict__ w_dec2,
    unsigned short* __restrict__ wb_enc2, unsigned short* __restrict__ wb_enc3,
    unsigned short* __restrict__ wb_dec1, unsigned short* __restrict__ wb_dec2)
{
    // folded weight prep: 46080 elements over the first 180 blocks
    {
        int g = blockIdx.x * 256 + threadIdx.x;
        if (g < 4608) wb_enc2[g] = f2bf(w_enc2[g]);
        else {
            g -= 4608;
            if (g < 18432) wb_enc3[g] = f2bf(w_enc3[g]);
            else {
                g -= 18432;
                if (g < 18432) wb_dec1[g] = f2bf(w_dec1[g]);
                else { g -= 18432; if (g < 4608) wb_dec2[g] = f2bf(w_dec2[g]); }
            }
        }
    }
    __shared__ float wsf[4][160];
    __shared__ int nsh[4][576];
    int t = threadIdx.x;
    int lane = t & 63, wave = t >> 6;
    int wbase = blockIdx.x * 256 + wave * 64;   // this wave's first row
    for (int e = lane; e < 160; e += 64) wsf[wave][e] = (e < 144) ? w[e] : b[e - 144];
    for (int e = lane; e < 576; e += 64)
        nsh[wave][e] = __builtin_nontemporal_load(&neigh[(size_t)wbase * 9 + e]);
    __builtin_amdgcn_wave_barrier();
    float f[9];
#pragma unroll
    for (int k = 0; k < 9; ++k) { int j = nsh[wave][lane * 9 + k]; f[k] = (j < 0) ? 0.0f : feat[j]; }
    float v[16];
#pragma unroll
    for (int co = 0; co < 16; ++co) {
        float a = wsf[wave][144 + co];
#pragma unroll
        for (int k = 0; k < 9; ++k) a += f[k] * wsf[wave][co * 9 + k];
        v[co] = fmaxf(a, 0.0f);
    }
#pragma unroll
    for (int co = 0; co < 16; ++co) {
        v[co] = fmaxf(v[co], __shfl_xor(v[co], 1));
        v[co] = fmaxf(v[co], __shfl_xor(v[co], 2));
    }
    if ((lane & 3) == 0) {
        uint4v o0, o1;
#pragma unroll
        for (int h = 0; h < 4; ++h)
            o0[h] = (unsigned int)f2bf(v[2 * h]) | (((unsigned int)f2bf(v[2 * h + 1])) << 16);
#pragma unroll
        for (int h = 0; h < 4; ++h)
            o1[h] = (unsigned int)f2bf(v[8 + 2 * h]) | (((unsigned int)f2bf(v[9 + 2 * h])) << 16);
        uint4v* dst = (uint4v*)(x7p + (size_t)((wbase + lane) >> 2) * 16);
        __builtin_nontemporal_store(o0, &dst[0]);
        __builtin_nontemporal_store(o1, &dst[1]);
    }
}

// ---------------- generic MFMA conv, TILES row-tiles of 64/block, wave-private staging ----------------
// SHIFT: gather src[neigh>>2] (fused unpool). POOL: 4:1 row-max epilogue.
// No __syncthreads anywhere: each wave stages its own 144 indices per tile.
template <int CIN, int COUT, bool SHIFT, bool POOL, int TILES>
__global__ __launch_bounds__(256) void conv_mfma(
    const unsigned short* __restrict__ src, const int* __restrict__ neigh,
    const unsigned short* __restrict__ wb, const float* __restrict__ bias,
    unsigned short* __restrict__ dst)
{
    constexpr int K  = 9 * CIN;
    constexpr int KT = (K + 31) / 32;
    constexpr int NT = COUT / 16;
    __shared__ int nsh[4][TILES * 144];
    int t = threadIdx.x;
    int lane = t & 63, wave = t >> 6;
    int rowbase = blockIdx.x * (64 * TILES);
#pragma unroll
    for (int tl = 0; tl < TILES; ++tl) {
        const int* srcn = &neigh[(size_t)(rowbase + tl * 64 + wave * 16) * 9];
        for (int e = lane; e < 144; e += 64) {
            int j = __builtin_nontemporal_load(&srcn[e]);
            if (SHIFT) j = (j < 0) ? -1 : (j >> 2);
            nsh[wave][tl * 144 + e] = j;
        }
    }
    __builtin_amdgcn_wave_barrier();
    int m    = lane & 15;
    int quad = lane >> 4;
    floatx4 acc[TILES][NT];
#pragma unroll
    for (int tl = 0; tl < TILES; ++tl)
#pragma unroll
        for (int n = 0; n < NT; ++n) acc[tl][n] = (floatx4){0.f, 0.f, 0.f, 0.f};
    for (int kt = 0; kt < KT; ++kt) {
        int k0 = kt * 32 + quad * 8;
        bf16x8 a[TILES];
#pragma unroll
        for (int tl = 0; tl < TILES; ++tl) {
            a[tl] = zero_bf16x8();
            if (k0 < K) {
                int nb = k0 / CIN;
                int ci = k0 % CIN;
                int j  = nsh[wave][tl * 144 + m * 9 + nb];
                if (j >= 0) a[tl] = *(const bf16x8*)(src + (size_t)j * CIN + ci);
            }
        }
#pragma unroll
        for (int n = 0; n < NT; ++n) {
            bf16x8 bfrag = zero_bf16x8();
            if (k0 < K) bfrag = *(const bf16x8*)(wb + (size_t)(n * 16 + m) * K + k0);
#pragma unroll
            for (int tl = 0; tl < TILES; ++tl)
                acc[tl][n] = __builtin_amdgcn_mfma_f32_16x16x32_bf16(a[tl], bfrag, acc[tl][n], 0, 0, 0);
        }
    }
#pragma unroll
    for (int tl = 0; tl < TILES; ++tl) {
        int tbase = rowbase + tl * 64;
        if (POOL) {
            int p = (tbase >> 2) + wave * 4 + quad;
#pragma unroll
            for (int n = 0; n < NT; ++n) {
                int cout = n * 16 + m;
                float vm = fmaxf(fmaxf(acc[tl][n][0], acc[tl][n][1]), fmaxf(acc[tl][n][2], acc[tl][n][3]));
                float v  = fmaxf(vm + bias[cout], 0.0f);
                __builtin_nontemporal_store(f2bf(v), &dst[(size_t)p * COUT + cout]);
            }
        } else {
            int grow = tbase + wave * 16 + quad * 4;
#pragma unroll
            for (int n = 0; n < NT; ++n) {
                int cout = n * 16 + m;
                float bv = bias[cout];
#pragma unroll
                for (int r = 0; r < 4; ++r) {
                    float v = fmaxf(acc[tl][n][r] + bv, 0.0f);
                    __builtin_nontemporal_store(f2bf(v), &dst[(size_t)(grow + r) * COUT + cout]);
                }
            }
        }
    }
}

// ---------------- head: Cin=16 bf16 -> 1 fp32; 2 rows/thread, wave-private staging ----------------
static __device__ __forceinline__ float dot2(unsigned int u, const float* w) {
    return bf2f((unsigned short)(u & 0xffffu)) * w[0] + bf2f((unsigned short)(u >> 16)) * w[1];
}
__global__ __launch_bounds__(256) void head_kernel(
    const unsigned short* __restrict__ x, const int* __restrict__ neigh,
    const float* __restrict__ w, const float* __restrict__ b, float* __restrict__ out)
{
    __shared__ float wsf[4][144];
    __shared__ int nsh[4][1152];
    int t = threadIdx.x;
    int lane = t & 63, wave = t >> 6;
    int base = blockIdx.x * 512;
    int r0base = base + wave * 64;          // rows for acc0
    int r1base = base + 256 + wave * 64;    // rows for acc1
    for (int e = lane; e < 144; e += 64) wsf[wave][e] = w[e];
    for (int e = lane; e < 576; e += 64) {
        nsh[wave][e]       = __builtin_nontemporal_load(&neigh[(size_t)r0base * 9 + e]);
        nsh[wave][576 + e] = __builtin_nontemporal_load(&neigh[(size_t)r1base * 9 + e]);
    }
    __builtin_amdgcn_wave_barrier();
    float acc0 = b[0], acc1 = b[0];
#pragma unroll
    for (int k = 0; k < 9; ++k) {
        int j0 = nsh[wave][lane * 9 + k];
        int j1 = nsh[wave][576 + lane * 9 + k];
        const float* wp = &wsf[wave][k * 16];
        if (j0 >= 0) {
            const uint2* r = (const uint2*)(x + (size_t)j0 * 16);
            uint2 a = r[0], c = r[1], d = r[2], e2 = r[3];
            acc0 += dot2(a.x, wp)      + dot2(a.y, wp + 2)  + dot2(c.x, wp + 4)  + dot2(c.y, wp + 6);
            acc0 += dot2(d.x, wp + 8)  + dot2(d.y, wp + 10) + dot2(e2.x, wp + 12) + dot2(e2.y, wp + 14);
        }
        if (j1 >= 0) {
            const uint2* r = (const uint2*)(x + (size_t)j1 * 16);
            uint2 a = r[0], c = r[1], d = r[2], e2 = r[3];
            acc1 += dot2(a.x, wp)      + dot2(a.y, wp + 2)  + dot2(c.x, wp + 4)  + dot2(c.y, wp + 6);
            acc1 += dot2(d.x, wp + 8)  + dot2(d.y, wp + 10) + dot2(e2.x, wp + 12) + dot2(e2.y, wp + 14);
        }
    }
    __builtin_nontemporal_store(acc0, &out[r0base + lane]);
    __builtin_nontemporal_store(acc1, &out[r1base + lane]);
}

extern "C" void kernel_launch(void* const* d_in, const int* in_sizes, int n_in,
                              void* d_out, int out_size, void* d_ws, size_t ws_size,
                              hipStream_t stream) {
    const float* features = (const float*)d_in[0];
    const int* neighs3 = (const int*)d_in[4];
    const int* neighs2 = (const int*)d_in[5];
    const int* neighs1 = (const int*)d_in[6];
    const float* w_enc1 = (const float*)d_in[7];
    const float* b_enc1 = (const float*)d_in[8];
    const float* w_enc2 = (const float*)d_in[9];
    const float* b_enc2 = (const float*)d_in[10];
    const float* w_enc3 = (const float*)d_in[11];
    const float* b_enc3 = (const float*)d_in[12];
    const float* w_dec1 = (const float*)d_in[13];
    const float* b_dec1 = (const float*)d_in[14];
    const float* w_dec2 = (const float*)d_in[15];
    const float* b_dec2 = (const float*)d_in[16];
    const float* w_head = (const float*)d_in[17];
    const float* b_head = (const float*)d_in[18];

    char* ws = (char*)d_ws;
    size_t off = 0;
    unsigned short* wb_enc2 = (unsigned short*)(ws + off); off += 4608 * 2;
    unsigned short* wb_enc3 = (unsigned short*)(ws + off); off += 18432 * 2;
    unsigned short* wb_dec1 = (unsigned short*)(ws + off); off += 18432 * 2;
    unsigned short* wb_dec2 = (unsigned short*)(ws + off); off += 4608 * 2;
    unsigned short* x7p   = (unsigned short*)(ws + off); off += (size_t)NN2 * 16 * 2;
    unsigned short* x6p   = (unsigned short*)(ws + off); off += (size_t)NN1 * 32 * 2;
    unsigned short* x6    = (unsigned short*)(ws + off); off += (size_t)NN1 * 64 * 2;
    unsigned short* x7dec = (unsigned short*)(ws + off); off += (size_t)NN2 * 32 * 2;
    unsigned short* x8dec = (unsigned short*)(ws + off); off += (size_t)NN3 * 16 * 2;

    // 1. enc1 + pool1 (+ folded weight prep): features -> x7p [N2,16]
    enc1pool_kernel<<<NN3 / 256, 256, 0, stream>>>(features, neighs3, w_enc1, b_enc1, x7p,
                                                   w_enc2, w_enc3, w_dec1, w_dec2,
                                                   wb_enc2, wb_enc3, wb_dec1, wb_dec2);
    // 2. enc2 + pool2: x7p -> x6p [N1,32]   (2 tiles/block)
    conv_mfma<16, 32, false, true, 2><<<NN2 / 128, 256, 0, stream>>>(x7p, neighs2, wb_enc2, b_enc2, x6p);
    // 3. enc3: x6p -> x6 [N1,64]            (1 tile/block)
    conv_mfma<32, 64, false, false, 1><<<NN1 / 64, 256, 0, stream>>>(x6p, neighs1, wb_enc3, b_enc3, x6);
    // 4. dec1 (fused unpool, gather x6[n>>2]): -> x7dec [N2,32]   (2 tiles/block)
    conv_mfma<64, 32, true, false, 2><<<NN2 / 128, 256, 0, stream>>>(x6, neighs2, wb_dec1, b_dec1, x7dec);
    // 5. dec2 (fused unpool, gather x7dec[n>>2]): -> x8dec [N3,16]  (4 tiles/block)
    conv_mfma<32, 16, true, false, 4><<<NN3 / 256, 256, 0, stream>>>(x7dec, neighs3, wb_dec2, b_dec2, x8dec);
    // 6. head: x8dec -> out [N3,1]f32       (2 rows/thread)
    head_kernel<<<NN3 / 512, 256, 0, stream>>>(x8dec, neighs3, w_head, b_head, (float*)d_out);
}